// Round 3
// baseline (1137.411 us; speedup 1.0000x reference)
//
#include <hip/hip_runtime.h>
#include <math.h>

// ---------------- workspace layout (float offsets) ----------------
#define WS_Z    0       // [304] per-row sumexp   (side*152 + b*19 + i)
#define WS_S    304     // [304] per-row sum(e*v)
#define WS_GB   640     // [2][8][361] unnormalized per-b gram (i<=j slots)
#define WS_WBF  6528    // conv_w as bf16 [768*128] -> 49152 float slots
// total 55680 floats

typedef __bf16 bf16x8 __attribute__((ext_vector_type(8)));
typedef float  f32x4  __attribute__((ext_vector_type(4)));
typedef const __attribute__((address_space(1))) unsigned int guint;
typedef       __attribute__((address_space(3))) unsigned int luint;

// ---------------- init: zero accumulators + convert W to bf16 ----------------
__global__ void k_init(const float* __restrict__ conv_w, float* __restrict__ ws,
                       float* __restrict__ out) {
    const int bx = blockIdx.x, tid = threadIdx.x;
    if (bx < 96) {
        __bf16* Wb = (__bf16*)(ws + WS_WBF);
        #pragma unroll
        for (int j = 0; j < 4; j++) {
            int idx = bx * 1024 + j * 256 + tid;
            Wb[idx] = (__bf16)conv_w[idx];
        }
    } else {
        for (int k = tid; k < 6416; k += 256) ws[k] = 0.f;
        if (tid < 2) out[tid] = 0.f;
    }
}

// ---------------- bilinear sample of t_logit row (65x65 -> 129x129) ----------------
__device__ __forceinline__ float t_resized(const float* __restrict__ Trow, int k) {
    int y = k / 129, x = k - y * 129;
    int y0 = y >> 1, x0 = x >> 1;
    int y1 = y0 + (y & 1), x1 = x0 + (x & 1);
    float fy = 0.5f * (float)(y & 1), fx = 0.5f * (float)(x & 1);
    float v00 = Trow[y0 * 65 + x0], v01 = Trow[y0 * 65 + x1];
    float v10 = Trow[y1 * 65 + x0], v11 = Trow[y1 * 65 + x1];
    float r0 = v00 + fx * (v01 - v00);
    float r1 = v10 + fx * (v11 - v10);
    return r0 + fy * (r1 - r0);
}

// ---------------- main: gram (0..95) + pi (96..623) + corner px (624..631) ----------
// pi block = (b, strip of 64 px), ALL 768 channels (12 chunks of 64, 4 quarters).
// Resize computed once per strip (was 4x). Per-pixel pi contribution finalized
// in-block (no WS_PART, no finalize dispatch).
// gram block = (side, b, 1/6th of k-range): unnormalized gram Σ e_i e_j and row
// Z,S accumulated; pair dots kept in registers across sub-tiles -> 190 atomics
// per block over 5776 addresses (was 100K over 722).
__launch_bounds__(256, 3)
__global__ void k_main(const float* __restrict__ s_out, const float* __restrict__ t_out,
                       const float* __restrict__ conv_w, const float* __restrict__ bias,
                       const float* __restrict__ s_logit, const float* __restrict__ t_logit,
                       float* __restrict__ ws, float* __restrict__ out) {
    __shared__ __align__(16) char lds[50176];
    const int tid = threadIdx.x;
    const int bx  = blockIdx.x;

    if (bx >= 96 && bx < 624) {
        // ================= pi role =================
        const int idx   = bx - 96;
        const int b     = idx / 66;
        const int strip = idx - b * 66;
        const int px0   = strip * 64;

        const int l = tid & 63, g = tid >> 6, q = l >> 4, n = l & 15;

        // ---- t source addressing (px rotated by 16 per 4-row group) ----
        const float* base_t = t_out + (size_t)(b * 768 + g * 16) * 4225;
        int off[4];
        #pragma unroll
        for (int j = 0; j < 4; j++) {
            int col = ((n * 4) + j * 16) & 63;
            off[j] = (j * 4 + q) * 4225 + px0 + col;
        }
        int colr[4];
        #pragma unroll
        for (int pt = 0; pt < 4; pt++)
            colr[pt] = (((pt * 16 + (n & 12) - q * 16) & 63)) + (n & 3);

        // double-buffered per-wave 4KB t slices at 17408 / 33792
        auto issue_t = [&](int cc) {
            char* lb = lds + 17408 + (cc & 1) * 16384 + g * 4096;
            const float* gb = base_t + (size_t)((cc / 3) * 192 + (cc % 3) * 64) * 4225;
            #pragma unroll
            for (int j = 0; j < 4; j++)
                __builtin_amdgcn_global_load_lds((guint*)(gb + off[j]),
                                                 (luint*)(lb + j * 1024), 16, 0, 0);
        };
        issue_t(0);
        issue_t(1);           // resize below hides both chunks' HBM latency

        __bf16* xs = (__bf16*)lds;               // 64 px x 136 c bf16

        // ---- bilinear resize 33x33 -> 65x65, 64-px strip, into xs[px][c] ----
        {
            const float* Sb = s_out + b * 128 * 1089;
            #pragma unroll
            for (int ii = 0; ii < 32; ii++) {
                int id2 = tid + ii * 256;
                int c = id2 >> 6, px = id2 & 63;
                int hw = px0 + px;
                int h = hw / 65, w = hw - h * 65;
                int y0 = h >> 1, x0 = w >> 1;
                int y1 = y0 + (h & 1), x1 = x0 + (w & 1);
                float wy = 0.5f * (float)(h & 1), wx = 0.5f * (float)(w & 1);
                const float* Sc = Sb + c * 1089;
                float v00 = Sc[y0 * 33 + x0], v01 = Sc[y0 * 33 + x1];
                float v10 = Sc[y1 * 33 + x0], v11 = Sc[y1 * 33 + x1];
                float r0 = v00 + wx * (v01 - v00);
                float r1 = v10 + wx * (v11 - v10);
                xs[px * 136 + c] = (__bf16)(r0 + wy * (r1 - r0));
            }
        }
        // barrier WITHOUT vmcnt drain (keep t0/t1 in flight)
        asm volatile("s_waitcnt lgkmcnt(0)" ::: "memory");
        __builtin_amdgcn_s_barrier();
        __builtin_amdgcn_sched_barrier(0);

        // ---- B fragments: full K=128, 4 px-groups, loaded once for all 12 chunks --
        bf16x8 bfrag[4][4];
        #pragma unroll
        for (int pt = 0; pt < 4; pt++)
            #pragma unroll
            for (int kf = 0; kf < 4; kf++)
                bfrag[pt][kf] = *(const bf16x8*)&xs[(pt * 16 + n) * 136 + kf * 32 + q * 8];

        // ---- A fragments + bias, double-buffered per chunk ----
        const __bf16* Wbf = (const __bf16*)(ws + WS_WBF);
        bf16x8 afr[2][4];
        f32x4  bq[2];
        auto load_a = [&](int cc) {
            int row0 = (cc / 3) * 192 + g * 16 + (cc % 3) * 64;
            const __bf16* Wr = Wbf + (size_t)(row0 + n) * 128 + q * 8;
            #pragma unroll
            for (int kf = 0; kf < 4; kf++) afr[cc & 1][kf] = *(const bf16x8*)(Wr + kf * 32);
            bq[cc & 1] = *(const f32x4*)&bias[row0 + q * 4];
        };
        load_a(0);

        // all waves done reading xs -> region free for quarter-merge scratch
        asm volatile("s_waitcnt lgkmcnt(0)" ::: "memory");
        __builtin_amdgcn_s_barrier();
        __builtin_amdgcn_sched_barrier(0);

        float Zt[4], St[4], Dd[4], Zs[4];
        #pragma unroll
        for (int pt = 0; pt < 4; pt++) { Zt[pt] = 0.f; St[pt] = 0.f; Dd[pt] = 0.f; Zs[pt] = 0.f; }
        float accZ = 0.f, accS = 0.f, accD = 0.f, accZ2 = 0.f;   // tid<64 per-px totals

        for (int cc = 0; cc < 12; cc++) {
            if (cc >= 1 && cc < 11) issue_t(cc + 1);
            if (cc < 11) asm volatile("s_waitcnt vmcnt(4)" ::: "memory");
            else         asm volatile("s_waitcnt vmcnt(0)" ::: "memory");
            if (cc < 11) load_a(cc + 1);

            const int cur = cc & 1;
            const float* tw = (const float*)(lds + 17408 + cur * 16384 + g * 4096);
            #pragma unroll
            for (int pt = 0; pt < 4; pt++) {
                f32x4 a0 = {0.f, 0.f, 0.f, 0.f};
                #pragma unroll
                for (int kf = 0; kf < 4; kf++)
                    a0 = __builtin_amdgcn_mfma_f32_16x16x32_bf16(afr[cur][kf], bfrag[pt][kf], a0, 0, 0, 0);
                #pragma unroll
                for (int r = 0; r < 4; r++) {
                    float tv  = tw[(q * 4 + r) * 64 + colr[pt]];
                    float s1v = a0[r] + bq[cur][r];
                    float e   = __expf(tv);
                    Zt[pt] += e;
                    St[pt]  = fmaf(e, tv,  St[pt]);
                    Dd[pt]  = fmaf(e, s1v, Dd[pt]);
                    Zs[pt] += __expf(s1v);
                }
            }

            if ((cc % 3) == 2) {
                // ---- quarter merge: 16 partitions (4 waves x 4 quads) per pixel ----
                asm volatile("s_waitcnt lgkmcnt(0)" ::: "memory");
                __builtin_amdgcn_s_barrier();       // scr free (prev read done / xs dead)
                __builtin_amdgcn_sched_barrier(0);
                float* scr = (float*)lds;
                int p = g * 4 + q;
                #pragma unroll
                for (int pt = 0; pt < 4; pt++) {
                    f32x4 v = {Zt[pt], St[pt], Dd[pt], Zs[pt]};
                    *(f32x4*)&scr[(pt * 16 + n) * 68 + p * 4] = v;
                    Zt[pt] = 0.f; St[pt] = 0.f; Dd[pt] = 0.f; Zs[pt] = 0.f;
                }
                asm volatile("s_waitcnt lgkmcnt(0)" ::: "memory");
                __builtin_amdgcn_s_barrier();
                __builtin_amdgcn_sched_barrier(0);
                if (tid < 64) {
                    #pragma unroll
                    for (int p2 = 0; p2 < 16; p2++) {
                        f32x4 v = *(const f32x4*)&scr[tid * 68 + p2 * 4];
                        accZ += v[0]; accS += v[1]; accD += v[2]; accZ2 += v[3];
                    }
                }
            }
        }

        // ---- per-pixel contribution, block-reduce, one atomic ----
        if (tid < 64) {
            float contrib = (accS - accD) / accZ - logf(accZ) + logf(accZ2);
            #pragma unroll
            for (int o = 32; o > 0; o >>= 1) contrib += __shfl_down(contrib, o);
            if (tid == 0) atomicAdd(out, contrib * (1.0f / 25958400.0f));
        }
    } else if (bx < 96) {
        // ================= gram role (unnormalized) =================
        const int side  = (bx >= 48) ? 1 : 0;
        const int rm    = side ? bx - 48 : bx;
        const int b     = rm / 6;
        const int split = rm - b * 6;
        const int kend  = min(16641, split * 3072 + 3072);

        float* pbuf = (float*)lds;                // [19][516]

        int pi_i = 0, pi_j = 0;
        if (tid < 190) {
            int t = tid;
            while (t >= 19 - pi_i) { t -= 19 - pi_i; pi_i++; }
            pi_j = pi_i + t;
        }

        float zacc[19], sacc[19];
        #pragma unroll
        for (int i = 0; i < 19; i++) { zacc[i] = 0.f; sacc[i] = 0.f; }
        float g0 = 0.f, g1 = 0.f, g2 = 0.f, g3 = 0.f;

        for (int k0 = split * 3072; k0 < kend; k0 += 512) {
            __syncthreads();                      // pbuf free (prev pairs done)
            #pragma unroll
            for (int i = 0; i < 19; i++) {
                const float* src = side ? (t_logit + (size_t)(b * 19 + i) * 4225)
                                        : (s_logit + (size_t)(b * 19 + i) * 16641);
                #pragma unroll
                for (int h = 0; h < 2; h++) {
                    int kl = tid + h * 256;
                    int k  = k0 + kl;
                    float p = 0.f;
                    if (k < 16641) {
                        float v = side ? t_resized(src, k) : src[k];
                        p = __expf(v);
                        zacc[i] += p;
                        sacc[i]  = fmaf(p, v, sacc[i]);
                    }
                    pbuf[i * 516 + kl] = p;
                }
            }
            __syncthreads();
            if (tid < 190) {
                const float* pi_ = &pbuf[pi_i * 516];
                const float* pj_ = &pbuf[pi_j * 516];
                #pragma unroll 2
                for (int kl = 0; kl < 512; kl += 16) {
                    float4 a0 = *(const float4*)&pi_[kl];      float4 c0 = *(const float4*)&pj_[kl];
                    float4 a1 = *(const float4*)&pi_[kl + 4];  float4 c1 = *(const float4*)&pj_[kl + 4];
                    float4 a2 = *(const float4*)&pi_[kl + 8];  float4 c2 = *(const float4*)&pj_[kl + 8];
                    float4 a3 = *(const float4*)&pi_[kl + 12]; float4 c3 = *(const float4*)&pj_[kl + 12];
                    g0 = fmaf(a0.x, c0.x, g0); g0 = fmaf(a0.y, c0.y, g0);
                    g0 = fmaf(a0.z, c0.z, g0); g0 = fmaf(a0.w, c0.w, g0);
                    g1 = fmaf(a1.x, c1.x, g1); g1 = fmaf(a1.y, c1.y, g1);
                    g1 = fmaf(a1.z, c1.z, g1); g1 = fmaf(a1.w, c1.w, g1);
                    g2 = fmaf(a2.x, c2.x, g2); g2 = fmaf(a2.y, c2.y, g2);
                    g2 = fmaf(a2.z, c2.z, g2); g2 = fmaf(a2.w, c2.w, g2);
                    g3 = fmaf(a3.x, c3.x, g3); g3 = fmaf(a3.y, c3.y, g3);
                    g3 = fmaf(a3.z, c3.z, g3); g3 = fmaf(a3.w, c3.w, g3);
                }
            }
        }
        if (tid < 190)
            atomicAdd(&ws[WS_GB + side * 2888 + b * 361 + pi_i * 19 + pi_j],
                      (g0 + g1) + (g2 + g3));

        // ---- row Z,S reduction: wave shuffles + cross-wave via LDS ----
        __syncthreads();                          // pbuf reusable as scratch
        float* redzs = (float*)lds;               // [19][4] z then [19][4] s
        {
            int w = tid >> 6, ln = tid & 63;
            #pragma unroll
            for (int i = 0; i < 19; i++) {
                float z = zacc[i], s = sacc[i];
                #pragma unroll
                for (int o = 32; o > 0; o >>= 1) { z += __shfl_down(z, o); s += __shfl_down(s, o); }
                if (ln == 0) { redzs[i * 4 + w] = z; redzs[76 + i * 4 + w] = s; }
            }
        }
        __syncthreads();
        if (tid < 19) {
            float Z = redzs[tid * 4] + redzs[tid * 4 + 1] + redzs[tid * 4 + 2] + redzs[tid * 4 + 3];
            float S = redzs[76 + tid * 4] + redzs[76 + tid * 4 + 1]
                    + redzs[76 + tid * 4 + 2] + redzs[76 + tid * 4 + 3];
            atomicAdd(&ws[WS_Z + side * 152 + b * 19 + tid], Z);
            atomicAdd(&ws[WS_S + side * 152 + b * 19 + tid], S);
        }
    } else {
        // ================= corner pixel (px 4224) role, one block per b ==========
        float* xc  = (float*)lds;          // 128
        float* red = (float*)lds + 128;    // 16
        const int b = bx - 624;
        if (tid < 128) xc[tid] = s_out[((size_t)b * 128 + tid) * 1089 + 1088];
        __syncthreads();
        float z = 0.f, s = 0.f, d = 0.f, z2 = 0.f;
        #pragma unroll
        for (int rep = 0; rep < 3; rep++) {
            int o = tid + rep * 256;
            const float* Wr = conv_w + (size_t)o * 128;
            float s1 = bias[o];
            for (int cc = 0; cc < 128; cc++) s1 = fmaf(Wr[cc], xc[cc], s1);
            float tv = t_out[((size_t)(b * 768 + o)) * 4225 + 4224];
            float e  = __expf(tv);
            z += e; s = fmaf(e, tv, s); d = fmaf(e, s1, d); z2 += __expf(s1);
        }
        for (int off = 32; off > 0; off >>= 1) {
            z += __shfl_down(z, off); s += __shfl_down(s, off);
            d += __shfl_down(d, off); z2 += __shfl_down(z2, off);
        }
        if ((tid & 63) == 0) {
            int wv = tid >> 6;
            red[wv] = z; red[4 + wv] = s; red[8 + wv] = d; red[12 + wv] = z2;
        }
        __syncthreads();
        if (tid == 0) {
            float Z = red[0] + red[1] + red[2] + red[3];
            float S = red[4] + red[5] + red[6] + red[7];
            float D = red[8] + red[9] + red[10] + red[11];
            float Z2 = red[12] + red[13] + red[14] + red[15];
            float contrib = (S - D) / Z - logf(Z) + logf(Z2);
            atomicAdd(out, contrib * (1.0f / 25958400.0f));
        }
    }
}

// ---------------- finalize lo_loss (1 block, 384 threads) ----------------
__global__ void k_fin(const float* __restrict__ ws, float* __restrict__ out) {
    __shared__ float Ms[361], Mt[361], El[38], rz[304], ns[19], nt[19], red[8];
    const int tid = threadIdx.x;
    if (tid < 304) rz[tid] = 1.0f / ws[WS_Z + tid];
    __syncthreads();
    if (tid < 38) {
        int side = (tid >= 19) ? 1 : 0, i = tid - side * 19;
        float e = 0.f;
        #pragma unroll
        for (int b = 0; b < 8; b++) {
            int row = side * 152 + b * 19 + i;
            e += ws[WS_S + row] * rz[row] - logf(ws[WS_Z + row]);
        }
        El[tid] = e;
    }
    __syncthreads();
    if (tid < 361) {
        int i = tid / 19, j = tid - i * 19;
        int lo = min(i, j), hi = max(i, j);
        float gs = 0.f, gt = 0.f;
        #pragma unroll
        for (int b = 0; b < 8; b++) {
            gs = fmaf(ws[WS_GB + b * 361 + lo * 19 + hi],
                      rz[b * 19 + lo] * rz[b * 19 + hi], gs);
            gt = fmaf(ws[WS_GB + 2888 + b * 361 + lo * 19 + hi],
                      rz[152 + b * 19 + lo] * rz[152 + b * 19 + hi], gt);
        }
        Ms[tid] = (El[hi] - gs) * 0.125f;
        Mt[tid] = (El[19 + hi] - gt) * 0.125f;
    }
    __syncthreads();
    if (tid < 19) {
        float as = 0.f, at = 0.f;
        for (int j = 0; j < 19; j++) {
            as = fmaf(Ms[tid * 19 + j], Ms[tid * 19 + j], as);
            at = fmaf(Mt[tid * 19 + j], Mt[tid * 19 + j], at);
        }
        ns[tid] = fmaxf(sqrtf(as), 1e-12f);
        nt[tid] = fmaxf(sqrtf(at), 1e-12f);
    }
    __syncthreads();
    float d = 0.f;
    if (tid < 361) {
        int i = tid / 19;
        float v = Ms[tid] / ns[i] - Mt[tid] / nt[i];
        d = v * v;
    }
    for (int off = 32; off > 0; off >>= 1) d += __shfl_down(d, off);
    if ((tid & 63) == 0) red[tid >> 6] = d;
    __syncthreads();
    if (tid == 0) out[1] = red[0] + red[1] + red[2] + red[3] + red[4] + red[5];
}

extern "C" void kernel_launch(void* const* d_in, const int* in_sizes, int n_in,
                              void* d_out, int out_size, void* d_ws, size_t ws_size,
                              hipStream_t stream) {
    const float* s_out   = (const float*)d_in[0];
    const float* t_out   = (const float*)d_in[1];
    const float* t_logit = (const float*)d_in[2];
    const float* s_logit = (const float*)d_in[3];
    const float* conv_w  = (const float*)d_in[4];
    const float* conv_b  = (const float*)d_in[5];
    float* out = (float*)d_out;
    float* ws  = (float*)d_ws;

    k_init<<<dim3(97), dim3(256), 0, stream>>>(conv_w, ws, out);
    k_main<<<dim3(632), dim3(256), 0, stream>>>(s_out, t_out, conv_w, conv_b,
                                                s_logit, t_logit, ws, out);
    k_fin<<<dim3(1), dim3(384), 0, stream>>>(ws, out);
}

// Round 4
// 269.676 us; speedup vs baseline: 4.2177x; 4.2177x over previous
//
#include <hip/hip_runtime.h>
#include <math.h>

// ---------------- workspace layout (float offsets) ----------------
#define WS_E0   0       // E_s[19]
#define WS_E1   19      // E_t[19]
#define WS_Z    1152    // row sumexp [304]
#define WS_WBF  2048    // conv_w as bf16 [768*128] -> 49152 float slots  [k_init..k_main]
#define WS_GP   2048    // gram private slices [176][190] f32 = 33440     [k_mid..k_final]
                        // (aliases WBF: W dead after k_main, GP written in k_mid)
#define WS_PART 51200   // quarter partials [4][8][4224][4] f32 = 540672 floats

typedef __bf16 bf16x8 __attribute__((ext_vector_type(8)));
typedef float  f32x4  __attribute__((ext_vector_type(4)));
typedef const __attribute__((address_space(1))) unsigned int guint;
typedef       __attribute__((address_space(3))) unsigned int luint;

// ---------------- init: zero accumulators + convert W to bf16 ----------------
__global__ void k_init(const float* __restrict__ conv_w, float* __restrict__ ws,
                       float* __restrict__ out) {
    const int bx = blockIdx.x, tid = threadIdx.x;
    if (bx < 96) {
        __bf16* Wb = (__bf16*)(ws + WS_WBF);
        #pragma unroll
        for (int j = 0; j < 4; j++) {
            int idx = bx * 1024 + j * 256 + tid;
            Wb[idx] = (__bf16)conv_w[idx];
        }
    } else {
        for (int k = tid; k < 2048; k += 256) ws[k] = 0.f;
        if (tid < 2) out[tid] = 0.f;
    }
}

// ---------------- bilinear sample of t_logit row (65x65 -> 129x129) ----------------
__device__ __forceinline__ float t_resized(const float* __restrict__ Trow, int k) {
    int y = k / 129, x = k - y * 129;
    int y0 = y >> 1, x0 = x >> 1;
    int y1 = y0 + (y & 1), x1 = x0 + (x & 1);
    float fy = 0.5f * (float)(y & 1), fx = 0.5f * (float)(x & 1);
    float v00 = Trow[y0 * 65 + x0], v01 = Trow[y0 * 65 + x1];
    float v10 = Trow[y1 * 65 + x0], v11 = Trow[y1 * 65 + x1];
    float r0 = v00 + fx * (v01 - v00);
    float r1 = v10 + fx * (v10 - v10);  // placeholder to be overwritten below
    r1 = v10 + fx * (v11 - v10);
    return r0 + fy * (r1 - r0);
}

// ---------------- main: rowstats (0..303) + pi (304..2415) + corner px (2416..2423) --
// pi block = (b, strip of 64 px, ch-quarter of 192). Per wave: 16 ch x 64 px.
// t_out: 3 chunks, ALL issued before first use (chunks 0/1 before the resize
// phase so resize hides their HBM latency; chunk 2 into the dead xs region).
// Raw s_barrier + lgkmcnt (NOT __syncthreads -> would drain vmcnt and kill the
// prefetch). Waits vmcnt(8)/(4)/(0) are safe under any compiler load placement.
__launch_bounds__(256, 3)
__global__ void k_main(const float* __restrict__ s_out, const float* __restrict__ t_out,
                       const float* __restrict__ conv_w, const float* __restrict__ bias,
                       const float* __restrict__ s_logit, const float* __restrict__ t_logit,
                       float* __restrict__ ws, float* __restrict__ out) {
    __shared__ __align__(16) char lds[50176];
    const int tid = threadIdx.x;
    const int bx  = blockIdx.x;

    if (bx >= 304 && bx < 2416) {
        // ================= pi role =================
        const int idx     = bx - 304;
        const int quarter = idx & 3;
        const int bs      = idx >> 2;
        const int b       = bs / 66;
        const int strip   = bs - b * 66;
        const int px0     = strip * 64;

        const int l = tid & 63, g = tid >> 6, q = l >> 4, n = l & 15;
        const int og = quarter * 192 + g * 16;

        // ---- t source addressing (px rotated by 16 per 4-row group) ----
        const float* base_t = t_out + (size_t)(b * 768 + og) * 4225;
        int off[4];
        #pragma unroll
        for (int j = 0; j < 4; j++) {
            int col = ((n * 4) + j * 16) & 63;
            off[j] = (j * 4 + q) * 4225 + px0 + col;
        }
        int colr[4];
        #pragma unroll
        for (int pt = 0; pt < 4; pt++)
            colr[pt] = (((pt * 16 + (n & 12) - q * 16) & 63)) + (n & 3);

        // buffers: B0 = lds+17408, B1 = lds+33792, B2 = lds+0 (xs region, dead
        // after bfrag extraction). Per-wave 4 KB slices.
        auto issue_t = [&](int cc) {
            char* lb = (cc == 2) ? (lds + g * 4096) : (lds + 17408 + cc * 16384 + g * 4096);
            const float* gb = base_t + (size_t)cc * 64 * 4225;
            #pragma unroll
            for (int j = 0; j < 4; j++)
                __builtin_amdgcn_global_load_lds((guint*)(gb + off[j]),
                                                 (luint*)(lb + j * 1024), 16, 0, 0);
        };

        // issue chunks 0 and 1 NOW: resize below hides their HBM latency
        issue_t(0);
        issue_t(1);

        __bf16* xs = (__bf16*)lds;               // 64 px x 136 c bf16

        // ---- bilinear resize 33x33 -> 65x65, 64-px strip, into xs[px][c] ----
        {
            const float* Sb = s_out + b * 128 * 1089;
            #pragma unroll
            for (int ii = 0; ii < 32; ii++) {
                int id2 = tid + ii * 256;
                int c = id2 >> 6, px = id2 & 63;
                int hw = px0 + px;
                int h = hw / 65, w = hw - h * 65;
                int y0 = h >> 1, x0 = w >> 1;
                int y1 = y0 + (h & 1), x1 = x0 + (w & 1);
                float wy = 0.5f * (float)(h & 1), wx = 0.5f * (float)(w & 1);
                const float* Sc = Sb + c * 1089;
                float v00 = Sc[y0 * 33 + x0], v01 = Sc[y0 * 33 + x1];
                float v10 = Sc[y1 * 33 + x0], v11 = Sc[y1 * 33 + x1];
                float r0 = v00 + wx * (v01 - v00);
                float r1 = v10 + wx * (v11 - v10);
                xs[px * 136 + c] = (__bf16)(r0 + wy * (r1 - r0));
            }
        }
        // barrier WITHOUT vmcnt drain (keep t0/t1 in flight)
        asm volatile("s_waitcnt lgkmcnt(0)" ::: "memory");
        __builtin_amdgcn_s_barrier();
        __builtin_amdgcn_sched_barrier(0);

        // ---- B fragments: full K=128, 4 px-groups, forced into registers ----
        bf16x8 bfrag[4][4];
        #pragma unroll
        for (int pt = 0; pt < 4; pt++)
            #pragma unroll
            for (int kf = 0; kf < 4; kf++)
                bfrag[pt][kf] = *(const bf16x8*)&xs[(pt * 16 + n) * 136 + kf * 32 + q * 8];

        // ---- A fragments + bias (W is L2-hot bf16): chunks 0,1 now; 2 in-loop ----
        const __bf16* Wbf = (const __bf16*)(ws + WS_WBF);
        bf16x8 afr[3][4];
        f32x4  bq[3];
        auto load_a = [&](int cc) {
            const __bf16* Wr = Wbf + (size_t)(og + cc * 64 + n) * 128 + q * 8;
            #pragma unroll
            for (int kf = 0; kf < 4; kf++) afr[cc][kf] = *(const bf16x8*)(Wr + kf * 32);
            bq[cc] = *(const f32x4*)&bias[og + cc * 64 + q * 4];
        };
        load_a(0);
        load_a(1);

        // all waves done reading xs -> safe to overwrite with t chunk 2
        asm volatile("s_waitcnt lgkmcnt(0)" ::: "memory");
        __builtin_amdgcn_s_barrier();
        __builtin_amdgcn_sched_barrier(0);
        issue_t(2);

        float Zt[4], St[4], Dd[4], Zs[4];
        #pragma unroll
        for (int pt = 0; pt < 4; pt++) { Zt[pt] = 0.f; St[pt] = 0.f; Dd[pt] = 0.f; Zs[pt] = 0.f; }

        #pragma unroll
        for (int c = 0; c < 3; c++) {
            if (c == 0)      asm volatile("s_waitcnt vmcnt(8)" ::: "memory");
            else if (c == 1) asm volatile("s_waitcnt vmcnt(4)" ::: "memory");
            else             asm volatile("s_waitcnt vmcnt(0)" ::: "memory");
            if (c == 1) load_a(2);   // L2 latency hides under chunk-1 compute

            const float* tw = (const float*)((c == 2) ? (lds + g * 4096)
                                                      : (lds + 17408 + c * 16384 + g * 4096));
            #pragma unroll
            for (int pt = 0; pt < 4; pt++) {
                f32x4 a0 = {0.f, 0.f, 0.f, 0.f};
                #pragma unroll
                for (int kf = 0; kf < 4; kf++)
                    a0 = __builtin_amdgcn_mfma_f32_16x16x32_bf16(afr[c][kf], bfrag[pt][kf], a0, 0, 0, 0);
                #pragma unroll
                for (int r = 0; r < 4; r++) {
                    float tv  = tw[(q * 4 + r) * 64 + colr[pt]];
                    float s1v = a0[r] + bq[c][r];
                    float e   = __expf(tv);
                    Zt[pt] += e;
                    St[pt]  = fmaf(e, tv,  St[pt]);
                    Dd[pt]  = fmaf(e, s1v, Dd[pt]);
                    Zs[pt] += __expf(s1v);
                }
            }
        }

        // ---- merge 16 partitions (4 waves x 4 quads) per pixel ----
        __syncthreads();                          // no VMEM outstanding here
        float* scr = (float*)lds;
        {
            int p = g * 4 + q;
            #pragma unroll
            for (int pt = 0; pt < 4; pt++) {
                f32x4 v = {Zt[pt], St[pt], Dd[pt], Zs[pt]};
                *(f32x4*)&scr[(pt * 16 + n) * 68 + p * 4] = v;
            }
        }
        __syncthreads();
        if (tid < 64) {
            float Z = 0.f, S = 0.f, D = 0.f, Z2 = 0.f;
            #pragma unroll
            for (int p = 0; p < 16; p++) {
                f32x4 v = *(const f32x4*)&scr[tid * 68 + p * 4];
                Z += v[0]; S += v[1]; D += v[2]; Z2 += v[3];
            }
            f32x4 o4 = {Z, S, D, Z2};
            *(f32x4*)&ws[WS_PART + (((size_t)quarter * 8 + b) * 4224 + px0 + tid) * 4] = o4;
        }
    } else if (bx < 304) {
        // ================= rowstats role =================
        float* red = (float*)lds;
        int row  = bx;
        int side = (row >= 152) ? 1 : 0;
        int r    = side ? row - 152 : row;
        const float* src = side ? (t_logit + r * 4225) : (s_logit + r * 16641);

        float z = 0.f, s = 0.f;
        #pragma unroll 4
        for (int k = tid; k < 16641; k += 256) {
            float v = side ? t_resized(src, k) : src[k];
            float e = __expf(v);
            z += e;
            s = fmaf(e, v, s);
        }
        for (int off = 32; off > 0; off >>= 1) { z += __shfl_down(z, off); s += __shfl_down(s, off); }
        if ((tid & 63) == 0) { red[tid >> 6] = z; red[4 + (tid >> 6)] = s; }
        __syncthreads();
        if (tid == 0) {
            float Z = red[0] + red[1] + red[2] + red[3];
            float S = red[4] + red[5] + red[6] + red[7];
            ws[WS_Z + row] = Z;
            atomicAdd(&ws[(side ? WS_E1 : WS_E0) + (r % 19)], S / Z - logf(Z));
        }
    } else {
        // ================= corner pixel (px 4224) role, one block per b ==========
        float* xc  = (float*)lds;          // 128
        float* red = (float*)lds + 128;    // 16
        const int b = bx - 2416;
        if (tid < 128) xc[tid] = s_out[((size_t)b * 128 + tid) * 1089 + 1088];
        __syncthreads();
        float z = 0.f, s = 0.f, d = 0.f, z2 = 0.f;
        #pragma unroll
        for (int rep = 0; rep < 3; rep++) {
            int o = tid + rep * 256;
            const float* Wr = conv_w + (size_t)o * 128;
            float s1 = bias[o];
            for (int cc = 0; cc < 128; cc++) s1 = fmaf(Wr[cc], xc[cc], s1);
            float tv = t_out[((size_t)(b * 768 + o)) * 4225 + 4224];
            float e  = __expf(tv);
            z += e; s = fmaf(e, tv, s); d = fmaf(e, s1, d); z2 += __expf(s1);
        }
        for (int off = 32; off > 0; off >>= 1) {
            z += __shfl_down(z, off); s += __shfl_down(s, off);
            d += __shfl_down(d, off); z2 += __shfl_down(z2, off);
        }
        if ((tid & 63) == 0) {
            int wv = tid >> 6;
            red[wv] = z; red[4 + wv] = s; red[8 + wv] = d; red[12 + wv] = z2;
        }
        __syncthreads();
        if (tid == 0) {
            float Z = red[0] + red[1] + red[2] + red[3];
            float S = red[4] + red[5] + red[6] + red[7];
            float D = red[8] + red[9] + red[10] + red[11];
            float Z2 = red[12] + red[13] + red[14] + red[15];
            float contrib = (S - D) / Z - logf(Z) + logf(Z2);
            atomicAdd(out, contrib * (1.0f / 25958400.0f));
        }
    }
}

// ---------------- mid: Gram (0..175, 3 sub-tiles each, private output) +
//                  pi finalize (176..307) ----------------
__global__ void k_mid(const float* __restrict__ s_logit, const float* __restrict__ t_logit,
                      float* __restrict__ ws, float* __restrict__ out) {
    __shared__ __align__(16) char lds[39296];
    const int tid = threadIdx.x;
    const int bx  = blockIdx.x;

    if (bx < 176) {
        float* pbuf  = (float*)lds;               // [19][516]
        float* rowiz = (float*)(lds + 39216);     // [19]
        int side = (bx >= 88) ? 1 : 0;
        int rm   = side ? bx - 88 : bx;
        int b = rm / 11, kt = rm - b * 11;

        if (tid < 19) rowiz[tid] = 1.0f / ws[WS_Z + side * 152 + b * 19 + tid];
        int pi_i = 0, pi_j = 0;
        if (tid < 190) {
            int t = tid;
            while (t >= 19 - pi_i) { t -= 19 - pi_i; pi_i++; }
            pi_j = pi_i + t;
        }
        __syncthreads();

        float g0 = 0.f, g1 = 0.f, g2 = 0.f, g3 = 0.f;
        const int kend = min(kt * 1536 + 1536, 16641);
        for (int k0 = kt * 1536; k0 < kend; k0 += 512) {
            for (int i = 0; i < 19; i++) {
                const float* src = side ? (t_logit + (size_t)(b * 19 + i) * 4225)
                                        : (s_logit + (size_t)(b * 19 + i) * 16641);
                float iz = rowiz[i];
                #pragma unroll
                for (int h = 0; h < 2; h++) {
                    int kl = tid + h * 256;
                    int k  = k0 + kl;
                    float p = 0.f;
                    if (k < 16641) {
                        float v = side ? t_resized(src, k) : src[k];
                        p = __expf(v) * iz;
                    }
                    pbuf[i * 516 + kl] = p;
                }
            }
            __syncthreads();
            if (tid < 190) {
                const float* pi_ = &pbuf[pi_i * 516];
                const float* pj_ = &pbuf[pi_j * 516];
                #pragma unroll 2
                for (int kl = 0; kl < 512; kl += 16) {
                    float4 a0 = *(const float4*)&pi_[kl];      float4 c0 = *(const float4*)&pj_[kl];
                    float4 a1 = *(const float4*)&pi_[kl + 4];  float4 c1 = *(const float4*)&pj_[kl + 4];
                    float4 a2 = *(const float4*)&pi_[kl + 8];  float4 c2 = *(const float4*)&pj_[kl + 8];
                    float4 a3 = *(const float4*)&pi_[kl + 12]; float4 c3 = *(const float4*)&pj_[kl + 12];
                    g0 = fmaf(a0.x, c0.x, g0); g0 = fmaf(a0.y, c0.y, g0);
                    g0 = fmaf(a0.z, c0.z, g0); g0 = fmaf(a0.w, c0.w, g0);
                    g1 = fmaf(a1.x, c1.x, g1); g1 = fmaf(a1.y, c1.y, g1);
                    g1 = fmaf(a1.z, c1.z, g1); g1 = fmaf(a1.w, c1.w, g1);
                    g2 = fmaf(a2.x, c2.x, g2); g2 = fmaf(a2.y, c2.y, g2);
                    g2 = fmaf(a2.z, c2.z, g2); g2 = fmaf(a2.w, c2.w, g2);
                    g3 = fmaf(a3.x, c3.x, g3); g3 = fmaf(a3.y, c3.y, g3);
                    g3 = fmaf(a3.z, c3.z, g3); g3 = fmaf(a3.w, c3.w, g3);
                }
            }
            __syncthreads();                      // pbuf reused next sub-tile
        }
        // private slice write: no atomics, coalesced 190 floats
        if (tid < 190)
            ws[WS_GP + (size_t)(side * 88 + rm) * 190 + tid] = (g0 + g1) + (g2 + g3);
    } else {
        // pi finalize: 132 blocks x 256 threads = 33792 = 8 b x 4224 px
        float* red = (float*)lds;
        int gp = (bx - 176) * 256 + tid;
        int b  = gp / 4224;
        int tp = gp - b * 4224;
        float Z = 0.f, S = 0.f, D = 0.f, Z2 = 0.f;
        #pragma unroll
        for (int qq = 0; qq < 4; qq++) {
            f32x4 v = *(const f32x4*)&ws[WS_PART + (((size_t)qq * 8 + b) * 4224 + tp) * 4];
            Z += v[0]; S += v[1]; D += v[2]; Z2 += v[3];
        }
        float contrib = (S - D) / Z - logf(Z) + logf(Z2);
        for (int off = 32; off > 0; off >>= 1) contrib += __shfl_down(contrib, off);
        if ((tid & 63) == 0) red[tid >> 6] = contrib;
        __syncthreads();
        if (tid == 0)
            atomicAdd(out, (red[0] + red[1] + red[2] + red[3]) * (1.0f / 25958400.0f));
    }
}

// ---------------- finalize lo_loss (1 block, 384 threads) ----------------
__global__ void k_final(const float* __restrict__ ws, float* __restrict__ out) {
    __shared__ float Ms[361], Mt[361], Gb[2][361], ns[19], nt[19];
    __shared__ float red[8];
    int tid = threadIdx.x;

    // reduce gram private slices (coalesced across tid at each sl step)
    if (tid < 380) {
        int side = (tid >= 190) ? 1 : 0, p = tid - side * 190;
        int i = 0, t = p;
        while (t >= 19 - i) { t -= 19 - i; i++; }
        int j = i + t;
        const float* base = ws + WS_GP + (size_t)side * 88 * 190 + p;
        float a0 = 0.f, a1 = 0.f, a2 = 0.f, a3 = 0.f;
        for (int sl = 0; sl < 88; sl += 4) {
            a0 += base[(size_t)(sl + 0) * 190];
            a1 += base[(size_t)(sl + 1) * 190];
            a2 += base[(size_t)(sl + 2) * 190];
            a3 += base[(size_t)(sl + 3) * 190];
        }
        Gb[side][i * 19 + j] = (a0 + a1) + (a2 + a3);
    }
    __syncthreads();
    if (tid < 361) {
        int i = tid / 19, j = tid - i * 19;
        int lo = min(i, j), hi = max(i, j);
        Ms[tid] = (ws[WS_E0 + hi] - Gb[0][lo * 19 + hi]) * 0.125f;
        Mt[tid] = (ws[WS_E1 + hi] - Gb[1][lo * 19 + hi]) * 0.125f;
    }
    __syncthreads();
    if (tid < 19) {
        float as = 0.f, at = 0.f;
        for (int j = 0; j < 19; j++) {
            as = fmaf(Ms[tid * 19 + j], Ms[tid * 19 + j], as);
            at = fmaf(Mt[tid * 19 + j], Mt[tid * 19 + j], at);
        }
        ns[tid] = fmaxf(sqrtf(as), 1e-12f);
        nt[tid] = fmaxf(sqrtf(at), 1e-12f);
    }
    __syncthreads();
    float d = 0.f;
    if (tid < 361) {
        int i = tid / 19;
        float v = Ms[tid] / ns[i] - Mt[tid] / nt[i];
        d = v * v;
    }
    for (int off = 32; off > 0; off >>= 1) d += __shfl_down(d, off);
    if ((tid & 63) == 0) red[tid >> 6] = d;
    __syncthreads();
    if (tid == 0) out[1] = red[0] + red[1] + red[2] + red[3] + red[4] + red[5];
}

extern "C" void kernel_launch(void* const* d_in, const int* in_sizes, int n_in,
                              void* d_out, int out_size, void* d_ws, size_t ws_size,
                              hipStream_t stream) {
    const float* s_out   = (const float*)d_in[0];
    const float* t_out   = (const float*)d_in[1];
    const float* t_logit = (const float*)d_in[2];
    const float* s_logit = (const float*)d_in[3];
    const float* conv_w  = (const float*)d_in[4];
    const float* conv_b  = (const float*)d_in[5];
    float* out = (float*)d_out;
    float* ws  = (float*)d_ws;

    k_init<<<dim3(97), dim3(256), 0, stream>>>(conv_w, ws, out);
    k_main<<<dim3(2424), dim3(256), 0, stream>>>(s_out, t_out, conv_w, conv_b,
                                                 s_logit, t_logit, ws, out);
    k_mid<<<dim3(308), dim3(256), 0, stream>>>(s_logit, t_logit, ws, out);
    k_final<<<dim3(1), dim3(384), 0, stream>>>(ws, out);
}